// Round 9
// baseline (3192.851 us; speedup 1.0000x reference)
//
#include <hip/hip_runtime.h>

// NeuralMemory scan: B=4, S=256, H=128, EXP=2, DEPTH=2.
// Round 9: fill the exchange-RT shadows. n-form weights (n_t = p0(1-a)+m) in
// registers. The fwd layer-0 matvec is linear in gu1:
//   x.n_t = eta*(x.n_{t-1}) + cP*(x.p0) - th*gu1_j*(x.k~),  bias folds with d+1
// so A/P/d dots + butterfly run in the B-poll shadow; after gh1 arrives only a
// 6-op register fixup remains. Layer-0 p0 prefetched to regs in the shadow
// (updates are pure-register). q/k come from per-thread global loads (k/q LDS
// buffers + one sync deleted -> 6 syncs/step). Layer-1 updates stay in the
// B shadow. 1 exchange-RT = the floor per exchange; 3 exchanges/step.

constexpr int HD  = 128;   // H
constexpr int SEQ = 256;   // S
constexpr int NB  = 4;     // B
constexpr int ED  = 256;   // H*EXP
constexpr int CW  = 64;    // hidden units per WG per layer (ED/NWG)
constexpr int NWG = 4;     // workgroups per batch

__device__ __forceinline__ float sigm(float x){ return 1.0f/(1.0f+__expf(-x)); }

// ---------------- kernel 1: q/k/v + gate scalars ----------------
__global__ __launch_bounds__(128) void qkv_kernel(
    const float* __restrict__ x,
    const float* __restrict__ Wq, const float* __restrict__ Wk, const float* __restrict__ Wv,
    const float* __restrict__ w_lr, const float* __restrict__ b_lr,
    const float* __restrict__ w_fg, const float* __restrict__ b_fg,
    const float* __restrict__ w_mo, const float* __restrict__ b_mo,
    float* __restrict__ qb, float* __restrict__ kb, float* __restrict__ vb,
    float* __restrict__ thb, float* __restrict__ alb, float* __restrict__ etb)
{
  const int bs = blockIdx.x;          // b*SEQ + s
  const int o  = threadIdx.x;         // 0..127
  __shared__ float xl[HD];
  __shared__ float rb[HD];
  xl[o] = x[(size_t)bs*HD + o];
  __syncthreads();

  float aq=0.f, ak=0.f, av=0.f;
  #pragma unroll 8
  for (int i=0;i<HD;i++){
    float xi = xl[i];
    aq = fmaf(xi, Wq[i*HD+o], aq);
    ak = fmaf(xi, Wk[i*HD+o], ak);
    av = fmaf(xi, Wv[i*HD+o], av);
  }
  float sq_ = aq*sigm(aq);
  float sk_ = ak*sigm(ak);
  float sv_ = av*sigm(av);

  auto bsum = [&](float v)->float {
    rb[o] = v; __syncthreads();
    for (int st=64; st>0; st>>=1){
      if (o < st) rb[o] += rb[o+st];
      __syncthreads();
    }
    float r = rb[0];
    __syncthreads();
    return r;
  };

  float nq = bsum(sq_*sq_);
  float nk = bsum(sk_*sk_);
  float dl = bsum(xl[o]*w_lr[o]);
  float df = bsum(xl[o]*w_fg[o]);
  float dm = bsum(xl[o]*w_mo[o]);

  qb[(size_t)bs*HD+o] = sq_ / fmaxf(sqrtf(nq), 1e-12f);
  kb[(size_t)bs*HD+o] = sk_ / fmaxf(sqrtf(nk), 1e-12f);
  vb[(size_t)bs*HD+o] = sv_;
  if (o==0){
    thb[bs] = sigm(dl + b_lr[0]) * 0.01f;   // MAX_LR
    alb[bs] = sigm(df + b_fg[0]);
    etb[bs] = sigm(dm + b_mo[0]);
  }
}

// ---------------- kernel 2: the sequential scan ----------------
__global__ __launch_bounds__(512, 1) void scan_kernel(
    const float* __restrict__ w1_0g, const float* __restrict__ b1_0g,
    const float* __restrict__ w2_0g, const float* __restrict__ b2_0g,
    const float* __restrict__ mw1_0g, const float* __restrict__ mb1_0g,
    const float* __restrict__ mw2_0g, const float* __restrict__ mb2_0g,
    const float* __restrict__ w1_1g, const float* __restrict__ b1_1g,
    const float* __restrict__ w2_1g, const float* __restrict__ b2_1g,
    const float* __restrict__ mw1_1g, const float* __restrict__ mb1_1g,
    const float* __restrict__ mw2_1g, const float* __restrict__ mb2_1g,
    const float* __restrict__ qbuf, const float* __restrict__ kbuf, const float* __restrict__ vbuf,
    const float* __restrict__ thb, const float* __restrict__ alb, const float* __restrict__ etb,
    unsigned long long* __restrict__ red, float* __restrict__ out)
{
  const int bid = blockIdx.x;
  const int b   = bid & 3;     // batch
  const int wg  = bid >> 2;    // 0..3 within batch
  const int tid = threadIdx.x;
  const int iG  = tid & 31;    // i-group (w1) / o-group (w2)
  const int jG  = tid >> 5;    // j-group 0..15
  const int i0  = iG*4;
  const int j0  = jG*4;
  const int c0  = wg*CW;

  __shared__ float pw1L[2][16][512];   // 64 KB p0 (w1), [plane][tid]
  __shared__ float pw2L[2][16][512];   // 64 KB p0 (w2)
  __shared__ float h1k[HD], h1q[HD], h2k[HD], gh1[HD];
  __shared__ float redbuf[8][256];
  __shared__ float b1p[2][CW], b1n[2][CW], b2p[2][32], b2n[2][32];

  // actual weights n = p0*(1-a) + m, carried in registers
  float nw1[2][16], nw2[2][16];
  {
    const float* w1s[2]  = {w1_0g,  w1_1g};
    const float* mw1s[2] = {mw1_0g, mw1_1g};
    const float* w2s[2]  = {w2_0g,  w2_1g};
    const float* mw2s[2] = {mw2_0g, mw2_1g};
    #pragma unroll
    for (int l=0;l<2;l++){
      #pragma unroll
      for (int jj=0;jj<4;jj++){
        #pragma unroll
        for (int ii=0;ii<4;ii++){
          int gi1 = (i0+ii)*ED + (c0+j0+jj);
          float p1 = w1s[l][gi1];
          pw1L[l][jj*4+ii][tid] = p1;
          nw1[l][jj*4+ii] = p1 + mw1s[l][gi1];   // n_{-1} = p0 + m0
          int gi2 = (c0+j0+jj)*HD + (i0+ii);
          float p2 = w2s[l][gi2];
          pw2L[l][jj*4+ii][tid] = p2;
          nw2[l][jj*4+ii] = p2 + mw2s[l][gi2];
        }
      }
    }
  }
  if (tid < CW){
    float p0a = b1_0g[c0+tid], p1a = b1_1g[c0+tid];
    b1p[0][tid] = p0a; b1n[0][tid] = p0a + mb1_0g[c0+tid];
    b1p[1][tid] = p1a; b1n[1][tid] = p1a + mb1_1g[c0+tid];
  } else if (tid < CW+32){
    int oo = tid - CW;
    float p0a = b2_0g[wg*32+oo], p1a = b2_1g[wg*32+oo];
    b2p[0][oo] = p0a; b2n[0][oo] = p0a + mb2_0g[wg*32+oo];
    b2p[1][oo] = p1a; b2n[1][oo] = p1a + mb2_1g[wg*32+oo];
  }

  auto pubstore = [&](int type, unsigned seq, int idx, float val){
    unsigned long long* p = red + (((b*3+type)*NWG + wg)*256 + idx);
    unsigned long long pk = ((unsigned long long)seq << 32) |
                            (unsigned long long)__float_as_uint(val);
    __hip_atomic_store(p, pk, __ATOMIC_RELAXED, __HIP_MEMORY_SCOPE_AGENT);
  };
  auto pollacc = [&](int type, unsigned seq, int idx, float own)->float{
    unsigned long long* base = red + ((b*3+type)*NWG)*256;
    const int wA=((wg+1)&3)*256+idx, wB=((wg+2)&3)*256+idx, wC=((wg+3)&3)*256+idx;
    unsigned long long vA = __hip_atomic_load(base+wA, __ATOMIC_RELAXED, __HIP_MEMORY_SCOPE_AGENT);
    unsigned long long vB = __hip_atomic_load(base+wB, __ATOMIC_RELAXED, __HIP_MEMORY_SCOPE_AGENT);
    unsigned long long vC = __hip_atomic_load(base+wC, __ATOMIC_RELAXED, __HIP_MEMORY_SCOPE_AGENT);
    float s = own; unsigned got = 0;
    while (got != 7u){
      if (!(got&1u)){
        if ((unsigned)(vA>>32)==seq){ s += __uint_as_float((unsigned)vA); got|=1u; }
        else vA = __hip_atomic_load(base+wA, __ATOMIC_RELAXED, __HIP_MEMORY_SCOPE_AGENT);
      }
      if (!(got&2u)){
        if ((unsigned)(vB>>32)==seq){ s += __uint_as_float((unsigned)vB); got|=2u; }
        else vB = __hip_atomic_load(base+wB, __ATOMIC_RELAXED, __HIP_MEMORY_SCOPE_AGENT);
      }
      if (!(got&4u)){
        if ((unsigned)(vC>>32)==seq){ s += __uint_as_float((unsigned)vC); got|=4u; }
        else vC = __hip_atomic_load(base+wC, __ATOMIC_RELAXED, __HIP_MEMORY_SCOPE_AGENT);
      }
    }
    return s;
  };

  // loop-carried per-thread state
  float u1_r[4], s1_r[4], u2_r[4], s2_r[4], h1k_r[4], v_r[4], vc_r = 0.f;
  float kprev4[4];   // k_t (this step's grad key), i0-range

  // forward from biased layer-0 pre-activations uq/uk (q_t-path, k_{t+1}-path).
  // ro = per-thread F1 residual (tid<128: q_t[tid]; 128..255: k_{t+1}[tid-128]).
  auto fwdFromU = [&](int t, bool writeOut, unsigned seq,
                      const float* uq, const float* uk, float ro){
    float sq1q[4];
    #pragma unroll
    for (int jj=0;jj<4;jj++){
      float vq = uq[jj], vk = uk[jj];
      u1_r[jj]=vk; s1_r[jj]=vk*sigm(vk); sq1q[jj]=vq*sigm(vq);
    }
    // ---- layer0 out partials (nw2[0] = n_t, updated before call) ----
    float oq[4]={0,0,0,0}, ok[4]={0,0,0,0};
    #pragma unroll
    for (int jj=0;jj<4;jj++){
      #pragma unroll
      for (int oo=0;oo<4;oo++){
        float w = nw2[0][jj*4+oo];
        oq[oo] = fmaf(sq1q[jj], w, oq[oo]);
        ok[oo] = fmaf(s1_r[jj], w, ok[oo]);
      }
    }
    #pragma unroll
    for (int oo=0;oo<4;oo++){
      oq[oo] += __shfl_xor(oq[oo], 32, 64);
      ok[oo] += __shfl_xor(ok[oo], 32, 64);
    }
    if (!(tid & 32)){
      int wv = tid>>6;
      #pragma unroll
      for (int oo=0;oo<4;oo++){
        redbuf[wv][i0+oo]     = oq[oo];
        redbuf[wv][128+i0+oo] = ok[oo];
      }
    }
    __syncthreads();                       // S4
    if (tid < 256){
      float p=0.f;
      #pragma unroll
      for (int w_=0; w_<8; w_++) p += redbuf[w_][tid];
      int o = tid & 127;
      if (o >= wg*32 && o < wg*32+32)
        p += b2n[0][o-wg*32];
      pubstore(1, seq, tid, p);
      float s0 = ro + pollacc(1, seq, tid, p);
      if (tid<128) h1q[o]=s0; else h1k[o]=s0;
    }
    __syncthreads();                       // S5
    // ---- layer1 u (nw1[1] = n_t, updated in B shadow) ----
    float aq2[4]={0,0,0,0}, ak2[4]={0,0,0,0};
    #pragma unroll
    for (int ii=0;ii<4;ii++){
      float qi = h1q[i0+ii], ki = h1k[i0+ii];
      h1k_r[ii] = ki;
      #pragma unroll
      for (int jj=0;jj<4;jj++){
        float w = nw1[1][jj*4+ii];
        aq2[jj] = fmaf(qi, w, aq2[jj]);
        ak2[jj] = fmaf(ki, w, ak2[jj]);
      }
    }
    #pragma unroll
    for (int d=1; d<32; d<<=1){
      #pragma unroll
      for (int jj=0;jj<4;jj++){
        aq2[jj] += __shfl_xor(aq2[jj], d, 64);
        ak2[jj] += __shfl_xor(ak2[jj], d, 64);
      }
    }
    float sq2q[4];
    #pragma unroll
    for (int jj=0;jj<4;jj++){
      float bb = b1n[1][j0+jj];
      float vq = aq2[jj]+bb, vk = ak2[jj]+bb;
      u2_r[jj]=vk; s2_r[jj]=vk*sigm(vk); sq2q[jj]=vq*sigm(vq);
    }
    // ---- layer1 out partials ----
    #pragma unroll
    for (int oo=0;oo<4;oo++){ oq[oo]=0.f; ok[oo]=0.f; }
    #pragma unroll
    for (int jj=0;jj<4;jj++){
      #pragma unroll
      for (int oo=0;oo<4;oo++){
        float w = nw2[1][jj*4+oo];
        oq[oo] = fmaf(sq2q[jj], w, oq[oo]);
        ok[oo] = fmaf(s2_r[jj], w, ok[oo]);
      }
    }
    #pragma unroll
    for (int oo=0;oo<4;oo++){
      oq[oo] += __shfl_xor(oq[oo], 32, 64);
      ok[oo] += __shfl_xor(ok[oo], 32, 64);
    }
    if (!(tid & 32)){
      int wv = tid>>6;
      #pragma unroll
      for (int oo=0;oo<4;oo++){
        redbuf[wv][i0+oo]     = oq[oo];
        redbuf[wv][128+i0+oo] = ok[oo];
      }
    }
    __syncthreads();                       // S6
    if (tid < 256){
      float p=0.f;
      #pragma unroll
      for (int w_=0; w_<8; w_++) p += redbuf[w_][tid];
      int o = tid & 127;
      if (o >= wg*32 && o < wg*32+32)
        p += b2n[1][o-wg*32];
      pubstore(2, seq, tid, p);
      float s0 = ((tid<128) ? h1q[o] : h1k[o]) + pollacc(2, seq, tid, p);
      if (tid<128){
        if (writeOut && o >= wg*32 && o < wg*32+32)
          out[((size_t)(b*SEQ + t))*HD + o] = s0;
      } else {
        h2k[o] = s0;
      }
    }
  };

  // ---- prologue: forward k_0 with n_{-1} = p0 + m0 (m0=0 pristine) ----
  {
    #pragma unroll
    for (int ii=0;ii<4;ii++){
      kprev4[ii] = kbuf[((size_t)b*SEQ + 0)*HD + i0+ii];
      v_r[ii]    = vbuf[((size_t)b*SEQ + 0)*HD + i0+ii];
    }
    if (tid < HD) vc_r = vbuf[((size_t)b*SEQ + 0)*HD + tid];
    float ro0 = 0.f;
    if (tid >= 128 && tid < 256)
      ro0 = kbuf[((size_t)b*SEQ + 0)*HD + (tid-128)];
    __syncthreads();   // init (LDS p0/biases) visible
    float ak0[4]={0,0,0,0};
    #pragma unroll
    for (int ii=0;ii<4;ii++){
      float ki = kprev4[ii];
      #pragma unroll
      for (int jj=0;jj<4;jj++)
        ak0[jj] = fmaf(ki, nw1[0][jj*4+ii], ak0[jj]);
    }
    #pragma unroll
    for (int d=1; d<32; d<<=1){
      #pragma unroll
      for (int jj=0;jj<4;jj++) ak0[jj] += __shfl_xor(ak0[jj], d, 64);
    }
    float uq0[4], uk0[4];
    #pragma unroll
    for (int jj=0;jj<4;jj++){
      float bb = b1n[0][j0+jj];
      uq0[jj] = bb;              // q-path = 0 vector -> bias only (discarded)
      uk0[jj] = ak0[jj] + bb;
    }
    fwdFromU(0, false, 1u, uq0, uk0, ro0);
  }

  float dPrev = 1.f;   // 1 - alpha_{-1}
  for (int t=0; t<SEQ; ++t){
    const int tn = (t < SEQ-1) ? t+1 : SEQ-1;
    // ---- early global loads: q_t, k_{t+1} (i0-range + residual scalar) ----
    float qv4[4], kv4[4];
    #pragma unroll
    for (int ii=0;ii<4;ii++){
      qv4[ii] = qbuf[((size_t)b*SEQ + t )*HD + i0+ii];
      kv4[ii] = kbuf[((size_t)b*SEQ + tn)*HD + i0+ii];
    }
    float ro = 0.f;
    if (tid < 128)      ro = qbuf[((size_t)b*SEQ + t )*HD + tid];
    else if (tid < 256) ro = kbuf[((size_t)b*SEQ + tn)*HD + (tid-128)];
    const float th = thb[b*SEQ+t];
    const float al = alb[b*SEQ+t];
    const float et = etb[b*SEQ+t];
    const float dcur = 1.f - al;
    const float cP = dcur - et*dPrev;
    __syncthreads();                       // S1: h2k from prev fwd visible
    // ---- g2v, gu2 (weights n_{t-1}) ----
    float g2v_r[4];
    #pragma unroll
    for (int ii=0;ii<4;ii++) g2v_r[ii] = 0.015625f*(h2k[i0+ii] - v_r[ii]);
    float acc[4]={0,0,0,0};
    #pragma unroll
    for (int oo=0;oo<4;oo++){
      float go = g2v_r[oo];
      #pragma unroll
      for (int jj=0;jj<4;jj++)
        acc[jj] = fmaf(go, nw2[1][jj*4+oo], acc[jj]);
    }
    #pragma unroll
    for (int d=1; d<32; d<<=1){
      #pragma unroll
      for (int jj=0;jj<4;jj++) acc[jj] += __shfl_xor(acc[jj], d, 64);
    }
    float gu2r[4];
    #pragma unroll
    for (int jj=0;jj<4;jj++){
      float u=u2_r[jj]; float sg=sigm(u);
      gu2r[jj] = acc[jj]*sg*fmaf(u, 1.f-sg, 1.f);
    }
    // ---- gh1 partial ----
    float a2[4]={0,0,0,0};
    #pragma unroll
    for (int jj=0;jj<4;jj++){
      float gj = gu2r[jj];
      #pragma unroll
      for (int ii=0;ii<4;ii++)
        a2[ii] = fmaf(gj, nw1[1][jj*4+ii], a2[ii]);
    }
    #pragma unroll
    for (int ii=0;ii<4;ii++) a2[ii] += __shfl_xor(a2[ii], 32, 64);
    if (!(tid & 32)){
      int wv = tid>>6;
      #pragma unroll
      for (int ii=0;ii<4;ii++) redbuf[wv][i0+ii] = a2[ii];
    }
    __syncthreads();                       // S2
    const unsigned seqB = (unsigned)(t+1);
    float pB = 0.f, g2vc = 0.f;
    if (tid < HD){
      #pragma unroll
      for (int w_=0;w_<8;w_++) pB += redbuf[w_][tid];
      pubstore(0, seqB, tid, pB);          // publish ASAP
      g2vc = 0.015625f*(h2k[tid] - vc_r);
    }
    // ================= B-POLL SHADOW =================
    // layer-1 n-updates (n_t = et*n_{t-1} + cP*p0 - th*grad)
    #pragma unroll
    for (int jj=0;jj<4;jj++){
      float g2j = gu2r[jj], s2j = s2_r[jj];
      #pragma unroll
      for (int ii=0;ii<4;ii++){
        int e = jj*4+ii;
        nw1[1][e] = fmaf(et, nw1[1][e],
                         fmaf(cP, pw1L[1][e][tid], -th*(h1k_r[ii]*g2j)));
        nw2[1][e] = fmaf(et, nw2[1][e],
                         fmaf(cP, pw2L[1][e][tid], -th*(s2j*g2v_r[ii])));
      }
    }
    if (iG==0){
      #pragma unroll
      for (int jj=0;jj<4;jj++)
        b1n[1][j0+jj] = fmaf(et, b1n[1][j0+jj],
                             fmaf(cP, b1p[1][j0+jj], -th*gu2r[jj]));
    }
    if (jG==0 && iG>=wg*8 && iG<wg*8+8){
      #pragma unroll
      for (int ii=0;ii<4;ii++)
        b2n[1][i0+ii-wg*32] = fmaf(et, b2n[1][i0+ii-wg*32],
                                   fmaf(cP, b2p[1][i0+ii-wg*32], -th*g2v_r[ii]));
    }
    // A/P/d precompute for fwd layer-0 + p0 prefetch into registers
    float p0w1[16], p0w2[16];
    #pragma unroll
    for (int e=0;e<16;e++){ p0w1[e]=pw1L[0][e][tid]; p0w2[e]=pw2L[0][e][tid]; }
    float Aq[4]={0,0,0,0}, Ak[4]={0,0,0,0}, Pq[4]={0,0,0,0}, Pk[4]={0,0,0,0};
    float dq=0.f, dk=0.f;
    #pragma unroll
    for (int ii=0;ii<4;ii++){
      float qi=qv4[ii], ki=kv4[ii], kp=kprev4[ii];
      dq = fmaf(qi, kp, dq);
      dk = fmaf(ki, kp, dk);
      #pragma unroll
      for (int jj=0;jj<4;jj++){
        float n = nw1[0][jj*4+ii], p = p0w1[jj*4+ii];
        Aq[jj]=fmaf(qi,n,Aq[jj]); Ak[jj]=fmaf(ki,n,Ak[jj]);
        Pq[jj]=fmaf(qi,p,Pq[jj]); Pk[jj]=fmaf(ki,p,Pk[jj]);
      }
    }
    #pragma unroll
    for (int d=1; d<32; d<<=1){
      #pragma unroll
      for (int jj=0;jj<4;jj++){
        Aq[jj]+=__shfl_xor(Aq[jj],d,64); Ak[jj]+=__shfl_xor(Ak[jj],d,64);
        Pq[jj]+=__shfl_xor(Pq[jj],d,64); Pk[jj]+=__shfl_xor(Pk[jj],d,64);
      }
      dq += __shfl_xor(dq,d,64);
      dk += __shfl_xor(dk,d,64);
    }
    float bo[4], bp[4];
    #pragma unroll
    for (int jj=0;jj<4;jj++){
      bo[jj]=b1n[0][j0+jj]; bp[jj]=b1p[0][j0+jj];
      Aq[jj]+=bo[jj]; Ak[jj]+=bo[jj];       // A+b_old
      Pq[jj]+=bp[jj]; Pk[jj]+=bp[jj];       // P+b_p
    }
    // prefetch v_{t+1} (consumed next iteration; old v consumed above)
    #pragma unroll
    for (int ii=0;ii<4;ii++)
      v_r[ii] = vbuf[((size_t)b*SEQ + tn)*HD + i0+ii];
    if (tid < HD) vc_r = vbuf[((size_t)b*SEQ + tn)*HD + tid];
    // ================= end shadow; poll B =================
    if (tid < HD)
      gh1[tid] = g2vc + pollacc(0, seqB, tid, pB);
    __syncthreads();                       // S3
    // ---- gu1 (weights nw2[0] = n_{t-1}) ----
    float gh1_r[4];
    #pragma unroll
    for (int ii=0;ii<4;ii++) gh1_r[ii] = gh1[i0+ii];
    #pragma unroll
    for (int jj=0;jj<4;jj++) acc[jj]=0.f;
    #pragma unroll
    for (int oo=0;oo<4;oo++){
      float go = gh1_r[oo];
      #pragma unroll
      for (int jj=0;jj<4;jj++)
        acc[jj] = fmaf(go, nw2[0][jj*4+oo], acc[jj]);
    }
    #pragma unroll
    for (int d=1; d<32; d<<=1){
      #pragma unroll
      for (int jj=0;jj<4;jj++) acc[jj] += __shfl_xor(acc[jj], d, 64);
    }
    float gu1r[4];
    #pragma unroll
    for (int jj=0;jj<4;jj++){
      float u=u1_r[jj]; float sg=sigm(u);
      gu1r[jj] = acc[jj]*sg*fmaf(u, 1.f-sg, 1.f);
    }
    // ---- layer-0 n-updates (pure registers: p0 prefetched) ----
    #pragma unroll
    for (int jj=0;jj<4;jj++){
      float g1j = gu1r[jj], s1j = s1_r[jj];
      #pragma unroll
      for (int ii=0;ii<4;ii++){
        int e = jj*4+ii;
        nw1[0][e] = fmaf(et, nw1[0][e],
                         fmaf(cP, p0w1[e], -th*(kprev4[ii]*g1j)));
        nw2[0][e] = fmaf(et, nw2[0][e],
                         fmaf(cP, p0w2[e], -th*(s1j*gh1_r[ii])));
      }
    }
    if (iG==0){
      #pragma unroll
      for (int jj=0;jj<4;jj++)
        b1n[0][j0+jj] = fmaf(et, bo[jj], fmaf(cP, bp[jj], -th*gu1r[jj]));
    }
    if (jG==0 && iG>=wg*8 && iG<wg*8+8){
      #pragma unroll
      for (int ii=0;ii<4;ii++)
        b2n[0][i0+ii-wg*32] = fmaf(et, b2n[0][i0+ii-wg*32],
                                   fmaf(cP, b2p[0][i0+ii-wg*32], -th*gh1_r[ii]));
    }
    // ---- layer-0 u via fixup: u = et*(A+b) + cP*(P+bp) - th*gu1*(d+1) ----
    float uqf[4], ukf[4];
    #pragma unroll
    for (int jj=0;jj<4;jj++){
      float g = th*gu1r[jj];
      uqf[jj] = fmaf(et, Aq[jj], fmaf(cP, Pq[jj], -g*(dq+1.f)));
      ukf[jj] = fmaf(et, Ak[jj], fmaf(cP, Pk[jj], -g*(dk+1.f)));
    }
    #pragma unroll
    for (int ii=0;ii<4;ii++) kprev4[ii] = kv4[ii];   // k~ for next step
    dPrev = dcur;
    fwdFromU(t, true, (unsigned)(t+2), uqf, ukf, ro);
  }
}

extern "C" void kernel_launch(void* const* d_in, const int* in_sizes, int n_in,
                              void* d_out, int out_size, void* d_ws, size_t ws_size,
                              hipStream_t stream)
{
  (void)in_sizes; (void)n_in; (void)out_size; (void)ws_size;
  const float* x    = (const float*)d_in[0];
  const float* Wq   = (const float*)d_in[1];
  const float* Wk   = (const float*)d_in[2];
  const float* Wv   = (const float*)d_in[3];
  const float* w_lr = (const float*)d_in[4];
  const float* b_lr = (const float*)d_in[5];
  const float* w_fg = (const float*)d_in[6];
  const float* b_fg = (const float*)d_in[7];
  const float* w_mo = (const float*)d_in[8];
  const float* b_mo = (const float*)d_in[9];
  const float* w1_0 = (const float*)d_in[10];
  const float* b1_0 = (const float*)d_in[11];
  const float* w2_0 = (const float*)d_in[12];
  const float* b2_0 = (const float*)d_in[13];
  const float* m_w1_0 = (const float*)d_in[14];
  const float* m_b1_0 = (const float*)d_in[15];
  const float* m_w2_0 = (const float*)d_in[16];
  const float* m_b2_0 = (const float*)d_in[17];
  const float* w1_1 = (const float*)d_in[18];
  const float* b1_1 = (const float*)d_in[19];
  const float* w2_1 = (const float*)d_in[20];
  const float* b2_1 = (const float*)d_in[21];
  const float* m_w1_1 = (const float*)d_in[22];
  const float* m_b1_1 = (const float*)d_in[23];
  const float* m_w2_1 = (const float*)d_in[24];
  const float* m_b2_1 = (const float*)d_in[25];

  float* wsf = (float*)d_ws;
  unsigned long long* red = (unsigned long long*)d_ws;   // 98304 B of slots
  float* qbuf = wsf + 32768;
  float* kbuf = qbuf + NB*SEQ*HD;
  float* vbuf = kbuf + NB*SEQ*HD;
  float* thb  = vbuf + NB*SEQ*HD;
  float* alb  = thb + NB*SEQ;
  float* etb  = alb + NB*SEQ;
  // ws re-poisoned to 0xAA each launch; 0xAAAAAAAA is never a valid seq tag.

  qkv_kernel<<<dim3(NB*SEQ), dim3(HD), 0, stream>>>(
      x, Wq, Wk, Wv, w_lr, b_lr, w_fg, b_fg, w_mo, b_mo,
      qbuf, kbuf, vbuf, thb, alb, etb);

  scan_kernel<<<dim3(NB*NWG), dim3(512), 0, stream>>>(
      w1_0, b1_0, w2_0, b2_0, m_w1_0, m_b1_0, m_w2_0, m_b2_0,
      w1_1, b1_1, w2_1, b2_1, m_w1_1, m_b1_1, m_w2_1, m_b2_1,
      qbuf, kbuf, vbuf, thb, alb, etb,
      red, (float*)d_out);
}

// Round 10
// 2392.868 us; speedup vs baseline: 1.3343x; 1.3343x over previous
//
#include <hip/hip_runtime.h>

// NeuralMemory scan: B=4, S=256, H=128, EXP=2, DEPTH=2.
// Round 10: revert R9's A/P/d shadow-fixup (regressed: 4x butterflies in a
// too-small poll shadow + VGPR cap). Back to R8 structure (n-form weights in
// regs, straight layer-0 dual matvec, LDS p0 reads in updates), keeping R9's
// benign removals: q/k per-thread GLOBAL loads (no kvecB/qvecB LDS, no
// pre-fwd sync -> 6 syncs/step) and v prefetch in the B shadow.
// Lesson (R9): shadows are ~full; only REMOVING chain work wins.

constexpr int HD  = 128;   // H
constexpr int SEQ = 256;   // S
constexpr int NB  = 4;     // B
constexpr int ED  = 256;   // H*EXP
constexpr int CW  = 64;    // hidden units per WG per layer (ED/NWG)
constexpr int NWG = 4;     // workgroups per batch

__device__ __forceinline__ float sigm(float x){ return 1.0f/(1.0f+__expf(-x)); }

// ---------------- kernel 1: q/k/v + gate scalars ----------------
__global__ __launch_bounds__(128) void qkv_kernel(
    const float* __restrict__ x,
    const float* __restrict__ Wq, const float* __restrict__ Wk, const float* __restrict__ Wv,
    const float* __restrict__ w_lr, const float* __restrict__ b_lr,
    const float* __restrict__ w_fg, const float* __restrict__ b_fg,
    const float* __restrict__ w_mo, const float* __restrict__ b_mo,
    float* __restrict__ qb, float* __restrict__ kb, float* __restrict__ vb,
    float* __restrict__ thb, float* __restrict__ alb, float* __restrict__ etb)
{
  const int bs = blockIdx.x;          // b*SEQ + s
  const int o  = threadIdx.x;         // 0..127
  __shared__ float xl[HD];
  __shared__ float rb[HD];
  xl[o] = x[(size_t)bs*HD + o];
  __syncthreads();

  float aq=0.f, ak=0.f, av=0.f;
  #pragma unroll 8
  for (int i=0;i<HD;i++){
    float xi = xl[i];
    aq = fmaf(xi, Wq[i*HD+o], aq);
    ak = fmaf(xi, Wk[i*HD+o], ak);
    av = fmaf(xi, Wv[i*HD+o], av);
  }
  float sq_ = aq*sigm(aq);
  float sk_ = ak*sigm(ak);
  float sv_ = av*sigm(av);

  auto bsum = [&](float v)->float {
    rb[o] = v; __syncthreads();
    for (int st=64; st>0; st>>=1){
      if (o < st) rb[o] += rb[o+st];
      __syncthreads();
    }
    float r = rb[0];
    __syncthreads();
    return r;
  };

  float nq = bsum(sq_*sq_);
  float nk = bsum(sk_*sk_);
  float dl = bsum(xl[o]*w_lr[o]);
  float df = bsum(xl[o]*w_fg[o]);
  float dm = bsum(xl[o]*w_mo[o]);

  qb[(size_t)bs*HD+o] = sq_ / fmaxf(sqrtf(nq), 1e-12f);
  kb[(size_t)bs*HD+o] = sk_ / fmaxf(sqrtf(nk), 1e-12f);
  vb[(size_t)bs*HD+o] = sv_;
  if (o==0){
    thb[bs] = sigm(dl + b_lr[0]) * 0.01f;   // MAX_LR
    alb[bs] = sigm(df + b_fg[0]);
    etb[bs] = sigm(dm + b_mo[0]);
  }
}

// ---------------- kernel 2: the sequential scan ----------------
__global__ __launch_bounds__(512, 1) void scan_kernel(
    const float* __restrict__ w1_0g, const float* __restrict__ b1_0g,
    const float* __restrict__ w2_0g, const float* __restrict__ b2_0g,
    const float* __restrict__ mw1_0g, const float* __restrict__ mb1_0g,
    const float* __restrict__ mw2_0g, const float* __restrict__ mb2_0g,
    const float* __restrict__ w1_1g, const float* __restrict__ b1_1g,
    const float* __restrict__ w2_1g, const float* __restrict__ b2_1g,
    const float* __restrict__ mw1_1g, const float* __restrict__ mb1_1g,
    const float* __restrict__ mw2_1g, const float* __restrict__ mb2_1g,
    const float* __restrict__ qbuf, const float* __restrict__ kbuf, const float* __restrict__ vbuf,
    const float* __restrict__ thb, const float* __restrict__ alb, const float* __restrict__ etb,
    unsigned long long* __restrict__ red, float* __restrict__ out)
{
  const int bid = blockIdx.x;
  const int b   = bid & 3;     // batch
  const int wg  = bid >> 2;    // 0..3 within batch
  const int tid = threadIdx.x;
  const int iG  = tid & 31;    // i-group (w1) / o-group (w2)
  const int jG  = tid >> 5;    // j-group 0..15
  const int i0  = iG*4;
  const int j0  = jG*4;
  const int c0  = wg*CW;

  __shared__ float pw1L[2][16][512];   // 64 KB p0 (w1), [plane][tid]
  __shared__ float pw2L[2][16][512];   // 64 KB p0 (w2)
  __shared__ float h1k[HD], h1q[HD], h2k[HD], gh1[HD];
  __shared__ float redbuf[8][256];
  __shared__ float b1p[2][CW], b1n[2][CW], b2p[2][32], b2n[2][32];

  // actual weights n = p0*(1-a) + m, carried in registers
  float nw1[2][16], nw2[2][16];
  {
    const float* w1s[2]  = {w1_0g,  w1_1g};
    const float* mw1s[2] = {mw1_0g, mw1_1g};
    const float* w2s[2]  = {w2_0g,  w2_1g};
    const float* mw2s[2] = {mw2_0g, mw2_1g};
    #pragma unroll
    for (int l=0;l<2;l++){
      #pragma unroll
      for (int jj=0;jj<4;jj++){
        #pragma unroll
        for (int ii=0;ii<4;ii++){
          int gi1 = (i0+ii)*ED + (c0+j0+jj);
          float p1 = w1s[l][gi1];
          pw1L[l][jj*4+ii][tid] = p1;
          nw1[l][jj*4+ii] = p1 + mw1s[l][gi1];   // n_{-1} = p0 + m0
          int gi2 = (c0+j0+jj)*HD + (i0+ii);
          float p2 = w2s[l][gi2];
          pw2L[l][jj*4+ii][tid] = p2;
          nw2[l][jj*4+ii] = p2 + mw2s[l][gi2];
        }
      }
    }
  }
  if (tid < CW){
    float p0a = b1_0g[c0+tid], p1a = b1_1g[c0+tid];
    b1p[0][tid] = p0a; b1n[0][tid] = p0a + mb1_0g[c0+tid];
    b1p[1][tid] = p1a; b1n[1][tid] = p1a + mb1_1g[c0+tid];
  } else if (tid < CW+32){
    int oo = tid - CW;
    float p0a = b2_0g[wg*32+oo], p1a = b2_1g[wg*32+oo];
    b2p[0][oo] = p0a; b2n[0][oo] = p0a + mb2_0g[wg*32+oo];
    b2p[1][oo] = p1a; b2n[1][oo] = p1a + mb2_1g[wg*32+oo];
  }

  auto pubstore = [&](int type, unsigned seq, int idx, float val){
    unsigned long long* p = red + (((b*3+type)*NWG + wg)*256 + idx);
    unsigned long long pk = ((unsigned long long)seq << 32) |
                            (unsigned long long)__float_as_uint(val);
    __hip_atomic_store(p, pk, __ATOMIC_RELAXED, __HIP_MEMORY_SCOPE_AGENT);
  };
  auto pollacc = [&](int type, unsigned seq, int idx, float own)->float{
    unsigned long long* base = red + ((b*3+type)*NWG)*256;
    const int wA=((wg+1)&3)*256+idx, wB=((wg+2)&3)*256+idx, wC=((wg+3)&3)*256+idx;
    unsigned long long vA = __hip_atomic_load(base+wA, __ATOMIC_RELAXED, __HIP_MEMORY_SCOPE_AGENT);
    unsigned long long vB = __hip_atomic_load(base+wB, __ATOMIC_RELAXED, __HIP_MEMORY_SCOPE_AGENT);
    unsigned long long vC = __hip_atomic_load(base+wC, __ATOMIC_RELAXED, __HIP_MEMORY_SCOPE_AGENT);
    float s = own; unsigned got = 0;
    while (got != 7u){
      if (!(got&1u)){
        if ((unsigned)(vA>>32)==seq){ s += __uint_as_float((unsigned)vA); got|=1u; }
        else vA = __hip_atomic_load(base+wA, __ATOMIC_RELAXED, __HIP_MEMORY_SCOPE_AGENT);
      }
      if (!(got&2u)){
        if ((unsigned)(vB>>32)==seq){ s += __uint_as_float((unsigned)vB); got|=2u; }
        else vB = __hip_atomic_load(base+wB, __ATOMIC_RELAXED, __HIP_MEMORY_SCOPE_AGENT);
      }
      if (!(got&4u)){
        if ((unsigned)(vC>>32)==seq){ s += __uint_as_float((unsigned)vC); got|=4u; }
        else vC = __hip_atomic_load(base+wC, __ATOMIC_RELAXED, __HIP_MEMORY_SCOPE_AGENT);
      }
    }
    return s;
  };

  // loop-carried per-thread state
  float u1_r[4], s1_r[4], u2_r[4], s2_r[4], h1k_r[4], v_r[4], vc_r = 0.f;
  float kprev4[4];   // k_t (this step's grad key), i0-range

  // forward from biased layer-0 pre-activations uq/uk.
  // ro = F1 residual (tid<128: q_t[tid]; 128..255: k_{t+1}[tid-128]).
  auto fwdFromU = [&](int t, bool writeOut, unsigned seq,
                      const float* uq, const float* uk, float ro){
    float sq1q[4];
    #pragma unroll
    for (int jj=0;jj<4;jj++){
      float vq = uq[jj], vk = uk[jj];
      u1_r[jj]=vk; s1_r[jj]=vk*sigm(vk); sq1q[jj]=vq*sigm(vq);
    }
    // ---- layer0 out partials (nw2[0] = n_t, updated before call) ----
    float oq[4]={0,0,0,0}, ok[4]={0,0,0,0};
    #pragma unroll
    for (int jj=0;jj<4;jj++){
      #pragma unroll
      for (int oo=0;oo<4;oo++){
        float w = nw2[0][jj*4+oo];
        oq[oo] = fmaf(sq1q[jj], w, oq[oo]);
        ok[oo] = fmaf(s1_r[jj], w, ok[oo]);
      }
    }
    #pragma unroll
    for (int oo=0;oo<4;oo++){
      oq[oo] += __shfl_xor(oq[oo], 32, 64);
      ok[oo] += __shfl_xor(ok[oo], 32, 64);
    }
    if (!(tid & 32)){
      int wv = tid>>6;
      #pragma unroll
      for (int oo=0;oo<4;oo++){
        redbuf[wv][i0+oo]     = oq[oo];
        redbuf[wv][128+i0+oo] = ok[oo];
      }
    }
    __syncthreads();                       // S4
    if (tid < 256){
      float p=0.f;
      #pragma unroll
      for (int w_=0; w_<8; w_++) p += redbuf[w_][tid];
      int o = tid & 127;
      if (o >= wg*32 && o < wg*32+32)
        p += b2n[0][o-wg*32];
      pubstore(1, seq, tid, p);
      float s0 = ro + pollacc(1, seq, tid, p);
      if (tid<128) h1q[o]=s0; else h1k[o]=s0;
    }
    __syncthreads();                       // S5
    // ---- layer1 u ----
    float aq2[4]={0,0,0,0}, ak2[4]={0,0,0,0};
    #pragma unroll
    for (int ii=0;ii<4;ii++){
      float qi = h1q[i0+ii], ki = h1k[i0+ii];
      h1k_r[ii] = ki;
      #pragma unroll
      for (int jj=0;jj<4;jj++){
        float w = nw1[1][jj*4+ii];
        aq2[jj] = fmaf(qi, w, aq2[jj]);
        ak2[jj] = fmaf(ki, w, ak2[jj]);
      }
    }
    #pragma unroll
    for (int d=1; d<32; d<<=1){
      #pragma unroll
      for (int jj=0;jj<4;jj++){
        aq2[jj] += __shfl_xor(aq2[jj], d, 64);
        ak2[jj] += __shfl_xor(ak2[jj], d, 64);
      }
    }
    float sq2q[4];
    #pragma unroll
    for (int jj=0;jj<4;jj++){
      float bb = b1n[1][j0+jj];
      float vq = aq2[jj]+bb, vk = ak2[jj]+bb;
      u2_r[jj]=vk; s2_r[jj]=vk*sigm(vk); sq2q[jj]=vq*sigm(vq);
    }
    // ---- layer1 out partials ----
    #pragma unroll
    for (int oo=0;oo<4;oo++){ oq[oo]=0.f; ok[oo]=0.f; }
    #pragma unroll
    for (int jj=0;jj<4;jj++){
      #pragma unroll
      for (int oo=0;oo<4;oo++){
        float w = nw2[1][jj*4+oo];
        oq[oo] = fmaf(sq2q[jj], w, oq[oo]);
        ok[oo] = fmaf(s2_r[jj], w, ok[oo]);
      }
    }
    #pragma unroll
    for (int oo=0;oo<4;oo++){
      oq[oo] += __shfl_xor(oq[oo], 32, 64);
      ok[oo] += __shfl_xor(ok[oo], 32, 64);
    }
    if (!(tid & 32)){
      int wv = tid>>6;
      #pragma unroll
      for (int oo=0;oo<4;oo++){
        redbuf[wv][i0+oo]     = oq[oo];
        redbuf[wv][128+i0+oo] = ok[oo];
      }
    }
    __syncthreads();                       // S6
    if (tid < 256){
      float p=0.f;
      #pragma unroll
      for (int w_=0; w_<8; w_++) p += redbuf[w_][tid];
      int o = tid & 127;
      if (o >= wg*32 && o < wg*32+32)
        p += b2n[1][o-wg*32];
      pubstore(2, seq, tid, p);
      float s0 = ((tid<128) ? h1q[o] : h1k[o]) + pollacc(2, seq, tid, p);
      if (tid<128){
        if (writeOut && o >= wg*32 && o < wg*32+32)
          out[((size_t)(b*SEQ + t))*HD + o] = s0;
      } else {
        h2k[o] = s0;
      }
    }
  };

  // ---- prologue: forward k_0 with n_{-1} = p0 + m0 (m0=0 pristine) ----
  {
    #pragma unroll
    for (int ii=0;ii<4;ii++){
      kprev4[ii] = kbuf[((size_t)b*SEQ + 0)*HD + i0+ii];
      v_r[ii]    = vbuf[((size_t)b*SEQ + 0)*HD + i0+ii];
    }
    if (tid < HD) vc_r = vbuf[((size_t)b*SEQ + 0)*HD + tid];
    float ro0 = 0.f;
    if (tid >= 128 && tid < 256)
      ro0 = kbuf[((size_t)b*SEQ + 0)*HD + (tid-128)];
    __syncthreads();   // init (LDS p0/biases) visible
    float ak0[4]={0,0,0,0};
    #pragma unroll
    for (int ii=0;ii<4;ii++){
      float ki = kprev4[ii];
      #pragma unroll
      for (int jj=0;jj<4;jj++)
        ak0[jj] = fmaf(ki, nw1[0][jj*4+ii], ak0[jj]);
    }
    #pragma unroll
    for (int d=1; d<32; d<<=1){
      #pragma unroll
      for (int jj=0;jj<4;jj++) ak0[jj] += __shfl_xor(ak0[jj], d, 64);
    }
    float uq0[4], uk0[4];
    #pragma unroll
    for (int jj=0;jj<4;jj++){
      float bb = b1n[0][j0+jj];
      uq0[jj] = bb;              // q-path = 0 vector (discarded)
      uk0[jj] = ak0[jj] + bb;
    }
    fwdFromU(0, false, 1u, uq0, uk0, ro0);
  }

  float dPrev = 1.f;   // 1 - alpha_{-1}
  for (int t=0; t<SEQ; ++t){
    const int tn = (t < SEQ-1) ? t+1 : SEQ-1;
    // ---- early global loads: q_t, k_{t+1} (hidden under S1 + backward) ----
    float qv4[4], kv4[4];
    #pragma unroll
    for (int ii=0;ii<4;ii++){
      qv4[ii] = qbuf[((size_t)b*SEQ + t )*HD + i0+ii];
      kv4[ii] = kbuf[((size_t)b*SEQ + tn)*HD + i0+ii];
    }
    float ro = 0.f;
    if (tid < 128)      ro = qbuf[((size_t)b*SEQ + t )*HD + tid];
    else if (tid < 256) ro = kbuf[((size_t)b*SEQ + tn)*HD + (tid-128)];
    const float th = thb[b*SEQ+t];
    const float al = alb[b*SEQ+t];
    const float et = etb[b*SEQ+t];
    const float dcur = 1.f - al;
    const float cP = dcur - et*dPrev;
    __syncthreads();                       // S1: h2k from prev fwd visible
    // ---- g2v, gu2 (weights n_{t-1}) ----
    float g2v_r[4];
    #pragma unroll
    for (int ii=0;ii<4;ii++) g2v_r[ii] = 0.015625f*(h2k[i0+ii] - v_r[ii]);
    float acc[4]={0,0,0,0};
    #pragma unroll
    for (int oo=0;oo<4;oo++){
      float go = g2v_r[oo];
      #pragma unroll
      for (int jj=0;jj<4;jj++)
        acc[jj] = fmaf(go, nw2[1][jj*4+oo], acc[jj]);
    }
    #pragma unroll
    for (int d=1; d<32; d<<=1){
      #pragma unroll
      for (int jj=0;jj<4;jj++) acc[jj] += __shfl_xor(acc[jj], d, 64);
    }
    float gu2r[4];
    #pragma unroll
    for (int jj=0;jj<4;jj++){
      float u=u2_r[jj]; float sg=sigm(u);
      gu2r[jj] = acc[jj]*sg*fmaf(u, 1.f-sg, 1.f);
    }
    // ---- gh1 partial ----
    float a2[4]={0,0,0,0};
    #pragma unroll
    for (int jj=0;jj<4;jj++){
      float gj = gu2r[jj];
      #pragma unroll
      for (int ii=0;ii<4;ii++)
        a2[ii] = fmaf(gj, nw1[1][jj*4+ii], a2[ii]);
    }
    #pragma unroll
    for (int ii=0;ii<4;ii++) a2[ii] += __shfl_xor(a2[ii], 32, 64);
    if (!(tid & 32)){
      int wv = tid>>6;
      #pragma unroll
      for (int ii=0;ii<4;ii++) redbuf[wv][i0+ii] = a2[ii];
    }
    __syncthreads();                       // S2
    const unsigned seqB = (unsigned)(t+1);
    float pB = 0.f, g2vc = 0.f;
    if (tid < HD){
      #pragma unroll
      for (int w_=0;w_<8;w_++) pB += redbuf[w_][tid];
      pubstore(0, seqB, tid, pB);          // publish ASAP
      g2vc = 0.015625f*(h2k[tid] - vc_r);
    }
    // ---- B-poll shadow: layer-1 n-updates + v prefetch (R8 amount) ----
    #pragma unroll
    for (int jj=0;jj<4;jj++){
      float g2j = gu2r[jj], s2j = s2_r[jj];
      #pragma unroll
      for (int ii=0;ii<4;ii++){
        int e = jj*4+ii;
        nw1[1][e] = fmaf(et, nw1[1][e],
                         fmaf(cP, pw1L[1][e][tid], -th*(h1k_r[ii]*g2j)));
        nw2[1][e] = fmaf(et, nw2[1][e],
                         fmaf(cP, pw2L[1][e][tid], -th*(s2j*g2v_r[ii])));
      }
    }
    if (iG==0){
      #pragma unroll
      for (int jj=0;jj<4;jj++)
        b1n[1][j0+jj] = fmaf(et, b1n[1][j0+jj],
                             fmaf(cP, b1p[1][j0+jj], -th*gu2r[jj]));
    }
    if (jG==0 && iG>=wg*8 && iG<wg*8+8){
      #pragma unroll
      for (int ii=0;ii<4;ii++)
        b2n[1][i0+ii-wg*32] = fmaf(et, b2n[1][i0+ii-wg*32],
                                   fmaf(cP, b2p[1][i0+ii-wg*32], -th*g2v_r[ii]));
    }
    // prefetch v_{t+1} (old v consumed above)
    #pragma unroll
    for (int ii=0;ii<4;ii++)
      v_r[ii] = vbuf[((size_t)b*SEQ + tn)*HD + i0+ii];
    if (tid < HD) vc_r = vbuf[((size_t)b*SEQ + tn)*HD + tid];
    // ---- poll B ----
    if (tid < HD)
      gh1[tid] = g2vc + pollacc(0, seqB, tid, pB);
    __syncthreads();                       // S3
    // ---- gu1 (weights nw2[0] = n_{t-1}) ----
    float gh1_r[4];
    #pragma unroll
    for (int ii=0;ii<4;ii++) gh1_r[ii] = gh1[i0+ii];
    #pragma unroll
    for (int jj=0;jj<4;jj++) acc[jj]=0.f;
    #pragma unroll
    for (int oo=0;oo<4;oo++){
      float go = gh1_r[oo];
      #pragma unroll
      for (int jj=0;jj<4;jj++)
        acc[jj] = fmaf(go, nw2[0][jj*4+oo], acc[jj]);
    }
    #pragma unroll
    for (int d=1; d<32; d<<=1){
      #pragma unroll
      for (int jj=0;jj<4;jj++) acc[jj] += __shfl_xor(acc[jj], d, 64);
    }
    float gu1r[4];
    #pragma unroll
    for (int jj=0;jj<4;jj++){
      float u=u1_r[jj]; float sg=sigm(u);
      gu1r[jj] = acc[jj]*sg*fmaf(u, 1.f-sg, 1.f);
    }
    // ---- layer-0 n-updates (LDS p0 reads, R8 style) ----
    #pragma unroll
    for (int jj=0;jj<4;jj++){
      float g1j = gu1r[jj], s1j = s1_r[jj];
      #pragma unroll
      for (int ii=0;ii<4;ii++){
        int e = jj*4+ii;
        nw1[0][e] = fmaf(et, nw1[0][e],
                         fmaf(cP, pw1L[0][e][tid], -th*(kprev4[ii]*g1j)));
        nw2[0][e] = fmaf(et, nw2[0][e],
                         fmaf(cP, pw2L[0][e][tid], -th*(s1j*gh1_r[ii])));
      }
    }
    if (iG==0){
      #pragma unroll
      for (int jj=0;jj<4;jj++)
        b1n[0][j0+jj] = fmaf(et, b1n[0][j0+jj],
                             fmaf(cP, b1p[0][j0+jj], -th*gu1r[jj]));
    }
    if (jG==0 && iG>=wg*8 && iG<wg*8+8){
      #pragma unroll
      for (int ii=0;ii<4;ii++)
        b2n[0][i0+ii-wg*32] = fmaf(et, b2n[0][i0+ii-wg*32],
                                   fmaf(cP, b2p[0][i0+ii-wg*32], -th*gh1_r[ii]));
    }
    // ---- layer-0 dual u with updated n_t (register q/k inputs) ----
    float aq[4]={0,0,0,0}, ak[4]={0,0,0,0};
    #pragma unroll
    for (int ii=0;ii<4;ii++){
      float qi = qv4[ii], ki = kv4[ii];
      #pragma unroll
      for (int jj=0;jj<4;jj++){
        float w = nw1[0][jj*4+ii];
        aq[jj] = fmaf(qi, w, aq[jj]);
        ak[jj] = fmaf(ki, w, ak[jj]);
      }
    }
    #pragma unroll
    for (int d=1; d<32; d<<=1){
      #pragma unroll
      for (int jj=0;jj<4;jj++){
        aq[jj] += __shfl_xor(aq[jj], d, 64);
        ak[jj] += __shfl_xor(ak[jj], d, 64);
      }
    }
    float uqf[4], ukf[4];
    #pragma unroll
    for (int jj=0;jj<4;jj++){
      float bb = b1n[0][j0+jj];   // wave-local RAW (writer iG==0 same wave)
      uqf[jj] = aq[jj] + bb;
      ukf[jj] = ak[jj] + bb;
    }
    #pragma unroll
    for (int ii=0;ii<4;ii++) kprev4[ii] = kv4[ii];   // k~ for next step
    dPrev = dcur;
    fwdFromU(t, true, (unsigned)(t+2), uqf, ukf, ro);
  }
}

extern "C" void kernel_launch(void* const* d_in, const int* in_sizes, int n_in,
                              void* d_out, int out_size, void* d_ws, size_t ws_size,
                              hipStream_t stream)
{
  (void)in_sizes; (void)n_in; (void)out_size; (void)ws_size;
  const float* x    = (const float*)d_in[0];
  const float* Wq   = (const float*)d_in[1];
  const float* Wk   = (const float*)d_in[2];
  const float* Wv   = (const float*)d_in[3];
  const float* w_lr = (const float*)d_in[4];
  const float* b_lr = (const float*)d_in[5];
  const float* w_fg = (const float*)d_in[6];
  const float* b_fg = (const float*)d_in[7];
  const float* w_mo = (const float*)d_in[8];
  const float* b_mo = (const float*)d_in[9];
  const float* w1_0 = (const float*)d_in[10];
  const float* b1_0 = (const float*)d_in[11];
  const float* w2_0 = (const float*)d_in[12];
  const float* b2_0 = (const float*)d_in[13];
  const float* m_w1_0 = (const float*)d_in[14];
  const float* m_b1_0 = (const float*)d_in[15];
  const float* m_w2_0 = (const float*)d_in[16];
  const float* m_b2_0 = (const float*)d_in[17];
  const float* w1_1 = (const float*)d_in[18];
  const float* b1_1 = (const float*)d_in[19];
  const float* w2_1 = (const float*)d_in[20];
  const float* b2_1 = (const float*)d_in[21];
  const float* m_w1_1 = (const float*)d_in[22];
  const float* m_b1_1 = (const float*)d_in[23];
  const float* m_w2_1 = (const float*)d_in[24];
  const float* m_b2_1 = (const float*)d_in[25];

  float* wsf = (float*)d_ws;
  unsigned long long* red = (unsigned long long*)d_ws;   // 98304 B of slots
  float* qbuf = wsf + 32768;
  float* kbuf = qbuf + NB*SEQ*HD;
  float* vbuf = kbuf + NB*SEQ*HD;
  float* thb  = vbuf + NB*SEQ*HD;
  float* alb  = thb + NB*SEQ;
  float* etb  = alb + NB*SEQ;
  // ws re-poisoned to 0xAA each launch; 0xAAAAAAAA is never a valid seq tag.

  qkv_kernel<<<dim3(NB*SEQ), dim3(HD), 0, stream>>>(
      x, Wq, Wk, Wv, w_lr, b_lr, w_fg, b_fg, w_mo, b_mo,
      qbuf, kbuf, vbuf, thb, alb, etb);

  scan_kernel<<<dim3(NB*NWG), dim3(512), 0, stream>>>(
      w1_0, b1_0, w2_0, b2_0, m_w1_0, m_b1_0, m_w2_0, m_b2_0,
      w1_1, b1_1, w2_1, b2_1, m_w1_1, m_b1_1, m_w2_1, m_b2_1,
      qbuf, kbuf, vbuf, thb, alb, etb,
      red, (float*)d_out);
}